// Round 3
// baseline (242.202 us; speedup 1.0000x reference)
//
#include <hip/hip_runtime.h>

#define B_  2
#define S_  2048
#define D_  1024
#define H_  16
#define DH_ 64
#define NDH (H_*DH_)   // 1024
#define BS_ (B_*S_)    // 4096
#define PER ((size_t)B_*H_*S_*DH_)   // 4M elements

typedef __bf16 bf16;
typedef bf16 bf16x8 __attribute__((ext_vector_type(8)));
typedef bf16 bf16x4 __attribute__((ext_vector_type(4)));
typedef float f32x4 __attribute__((ext_vector_type(4)));
typedef short s16x4 __attribute__((ext_vector_type(4)));

// softmax scale folded into Q: 0.125 * log2(e); flash kernel then uses exp2
#define QSCALE 0.18033688011112042f

#define AS1 __attribute__((address_space(1)))
#define AS3 __attribute__((address_space(3)))
__device__ inline void gld16(const bf16* g, bf16* l) {
    __builtin_amdgcn_global_load_lds((const AS1 void*)g, (AS3 void*)l, 16, 0, 0);
}

__device__ inline s16x4 bc4(bf16x4 v) { union { bf16x4 b; s16x4 s; } u; u.b = v; return u.s; }

// ---------------- fused prep: cast x -> bf16  +  transpose-cast 4 weight mats ----------------
__global__ __launch_bounds__(256) void prep(
        const float* __restrict__ x,
        const float* __restrict__ W0, const float* __restrict__ W1,
        const float* __restrict__ W2, const float* __restrict__ W3,
        bf16* __restrict__ xb, bf16* __restrict__ T0, bf16* __restrict__ T1,
        bf16* __restrict__ T2, bf16* __restrict__ T3) {
    __shared__ float T[32][33];
    int bid = blockIdx.x, t = threadIdx.x;
    if (bid < 4096) {
        int i = (bid * 256 + t) * 4;
        float4 v = *(const float4*)(x + i);
        bf16x4 o = { (bf16)v.x, (bf16)v.y, (bf16)v.z, (bf16)v.w };
        *(bf16x4*)(xb + i) = o;
        return;
    }
    int r2 = bid - 4096;
    int z = r2 >> 10, w = r2 & 1023;
    const float* W = (z == 0) ? W0 : (z == 1) ? W1 : (z == 2) ? W2 : W3;
    bf16* Wt = (z == 0) ? T0 : (z == 1) ? T1 : (z == 2) ? T2 : T3;
    int k0 = (w >> 5) * 32, n0 = (w & 31) * 32;
    int r = t >> 3, c = (t & 7) * 4;
    float4 v = *(const float4*)(W + (size_t)(k0 + r) * 1024 + n0 + c);
    T[c + 0][r] = v.x; T[c + 1][r] = v.y; T[c + 2][r] = v.z; T[c + 3][r] = v.w;
    __syncthreads();
    bf16x4 o = { (bf16)T[r][c], (bf16)T[r][c + 1], (bf16)T[r][c + 2], (bf16)T[r][c + 3] };
    *(bf16x4*)(Wt + (size_t)(n0 + r) * 1024 + k0 + c) = o;
}

// ---------------- fused QKV GEMM: 128x128 tile, global_load_lds ----------------
// Q gets the softmax scale (QSCALE) folded in (fp32, before bf16 round).
__global__ __launch_bounds__(256) void qkv_gemm(
        const bf16* __restrict__ A, const bf16* __restrict__ Bt,
        const float* __restrict__ bq, const float* __restrict__ bk,
        const float* __restrict__ bv, bf16* __restrict__ Qout, bf16* __restrict__ Vt) {
    __shared__ __align__(16) bf16 As[128 * 32];
    __shared__ __align__(16) bf16 Bs[128 * 32];
    int tid = threadIdx.x, wave = tid >> 6, lane = tid & 63;
    int quad = lane >> 4, l16 = lane & 15;
    int bm = blockIdx.y * 128, bn = blockIdx.x * 128;
    int wm = (wave >> 1) * 64, wn = (wave & 1) * 64;

    int sr = lane >> 2, sc = (lane & 3) * 8;
    const bf16* Ag0 = A + (size_t)(bm + (wave * 2 + 0) * 16 + sr) * 1024 + sc;
    const bf16* Ag1 = A + (size_t)(bm + (wave * 2 + 1) * 16 + sr) * 1024 + sc;
    const bf16* Bg0 = Bt + (size_t)(bn + (wave * 2 + 0) * 16 + sr) * 1024 + sc;
    const bf16* Bg1 = Bt + (size_t)(bn + (wave * 2 + 1) * 16 + sr) * 1024 + sc;
    bf16* Al0 = &As[(wave * 2 + 0) * 512];
    bf16* Al1 = &As[(wave * 2 + 1) * 512];
    bf16* Bl0 = &Bs[(wave * 2 + 0) * 512];
    bf16* Bl1 = &Bs[(wave * 2 + 1) * 512];

    f32x4 acc[4][4] = {};

    for (int k0 = 0; k0 < 1024; k0 += 32) {
        gld16(Ag0 + k0, Al0);
        gld16(Ag1 + k0, Al1);
        gld16(Bg0 + k0, Bl0);
        gld16(Bg1 + k0, Bl1);
        __syncthreads();
        bf16x8 af[4], bfr[4];
        #pragma unroll
        for (int i = 0; i < 4; ++i)
            af[i] = *(const bf16x8*)&As[(wm + i * 16 + l16) * 32 + quad * 8];
        #pragma unroll
        for (int j = 0; j < 4; ++j)
            bfr[j] = *(const bf16x8*)&Bs[(wn + j * 16 + l16) * 32 + quad * 8];
        #pragma unroll
        for (int i = 0; i < 4; ++i)
          #pragma unroll
          for (int j = 0; j < 4; ++j)
            acc[i][j] = __builtin_amdgcn_mfma_f32_16x16x32_bf16(af[i], bfr[j], acc[i][j], 0, 0, 0);
        __syncthreads();
    }

    #pragma unroll
    for (int i = 0; i < 4; ++i)
      #pragma unroll
      for (int j = 0; j < 4; ++j) {
        int col = bn + wn + j * 16 + l16;
        float bias = (col < 1024) ? bq[col] : (col < 2048) ? bk[col - 1024] : bv[col - 2048];
        int qkv = col >> 10, cw = col & 1023;
        int hh = cw >> 6, d = cw & 63;
        int row0 = bm + wm + i * 16 + quad * 4;
        int bb = row0 >> 11, s0 = row0 & 2047;
        if (qkv < 2) {
            float scl = (qkv == 0) ? QSCALE : 1.0f;
            #pragma unroll
            for (int r = 0; r < 4; ++r)
                Qout[(size_t)qkv * PER + (((size_t)bb * H_ + hh) * S_ + s0 + r) * DH_ + d] =
                    (bf16)((acc[i][j][r] + bias) * scl);
        } else {
            bf16x4 pack;
            #pragma unroll
            for (int r = 0; r < 4; ++r) pack[r] = (bf16)(acc[i][j][r] + bias);
            *(bf16x4*)&Vt[(((size_t)bb * H_ + hh) * DH_ + d) * S_ + s0] = pack;
        }
      }
}

// ---------------- output-projection GEMM: 128x64 tile (2 blocks/CU), fp32 out + bias ----------------
__global__ __launch_bounds__(256) void gemm_proj(
        const bf16* __restrict__ A, const bf16* __restrict__ Bt,
        const float* __restrict__ bias, float* __restrict__ out) {
    __shared__ __align__(16) bf16 As[128 * 32];
    __shared__ __align__(16) bf16 Bs[64 * 32];
    int tid = threadIdx.x, wave = tid >> 6, lane = tid & 63;
    int quad = lane >> 4, l16 = lane & 15;
    int bm = blockIdx.y * 128, bn = blockIdx.x * 64;
    int wm = (wave >> 1) * 64, wn = (wave & 1) * 32;

    int sr = lane >> 2, sc = (lane & 3) * 8;
    const bf16* Ag0 = A + (size_t)(bm + (wave * 2 + 0) * 16 + sr) * 1024 + sc;
    const bf16* Ag1 = A + (size_t)(bm + (wave * 2 + 1) * 16 + sr) * 1024 + sc;
    const bf16* Bg0 = Bt + (size_t)(bn + wave * 16 + sr) * 1024 + sc;
    bf16* Al0 = &As[(wave * 2 + 0) * 512];
    bf16* Al1 = &As[(wave * 2 + 1) * 512];
    bf16* Bl0 = &Bs[wave * 512];

    f32x4 acc[4][2] = {};

    for (int k0 = 0; k0 < 1024; k0 += 32) {
        gld16(Ag0 + k0, Al0);
        gld16(Ag1 + k0, Al1);
        gld16(Bg0 + k0, Bl0);
        __syncthreads();
        bf16x8 af[4], bfr[2];
        #pragma unroll
        for (int i = 0; i < 4; ++i)
            af[i] = *(const bf16x8*)&As[(wm + i * 16 + l16) * 32 + quad * 8];
        #pragma unroll
        for (int j = 0; j < 2; ++j)
            bfr[j] = *(const bf16x8*)&Bs[(wn + j * 16 + l16) * 32 + quad * 8];
        #pragma unroll
        for (int i = 0; i < 4; ++i)
          #pragma unroll
          for (int j = 0; j < 2; ++j)
            acc[i][j] = __builtin_amdgcn_mfma_f32_16x16x32_bf16(af[i], bfr[j], acc[i][j], 0, 0, 0);
        __syncthreads();
    }

    #pragma unroll
    for (int i = 0; i < 4; ++i)
      #pragma unroll
      for (int j = 0; j < 2; ++j) {
        int col = bn + wn + j * 16 + l16;
        float b = bias[col];
        #pragma unroll
        for (int r = 0; r < 4; ++r) {
            int row = bm + wm + i * 16 + quad * 4 + r;
            out[(size_t)row * 1024 + col] = acc[i][j][r] + b;
        }
      }
}

// ---------------- flash attention v7: swapped QK^T + in-register P via K=16 PV MFMAs ----------------
// grid (32 bh, 32 pairs), 256 thr. Block handles q-tiles {p, 63-p}: uniform ~33 kt iters.
// Q pre-scaled by 0.125*log2e -> exp2.
// Swapped QK (mfma(K,Q)) leaves lane(l16,quad) holding P[q=l16][kv=ns*16+quad*4+r] — which is
// EXACTLY the A-fragment of mfma_f32_16x16x16_bf16 (A[row=l16][k=quad*4+j]). So P never touches
// LDS: no ds_write/ds_read/lgkm round-trip, no bank conflicts, no pipelining needed.
// All K/V loads issued up-front per iteration so V latency hides under QK+exp.
__global__ __launch_bounds__(256) void flash7(
        const bf16* __restrict__ Q, const bf16* __restrict__ K,
        const bf16* __restrict__ Vt, bf16* __restrict__ O) {
    int bh = blockIdx.x;
    int b = bh >> 4, h = bh & 15;
    int pr = blockIdx.y;                 // 0..31
    int tid = threadIdx.x;
    int wave = tid >> 6, lane = tid & 63;
    int quad = lane >> 4, l16 = lane & 15;

    __shared__ float redO[4][4][64][4];   // [srcwave][ds][lane][r]  16 KB
    __shared__ float redL[4][2][4][4];

    const bf16* Qb = Q + (size_t)bh * S_ * DH_;
    const bf16* Kb = K + (size_t)bh * S_ * DH_;
    const bf16* Vb = Vt + (size_t)bh * DH_ * S_;

    bf16x4 ones4;
    #pragma unroll
    for (int j = 0; j < 4; ++j) ones4[j] = (l16 == 0) ? (bf16)1.0f : (bf16)0.0f;
    s16x4 onesB = bc4(ones4);

    // loop-invariant lane base addresses
    const bf16* Kp[4];
    #pragma unroll
    for (int ns = 0; ns < 4; ++ns) Kp[ns] = Kb + (size_t)(ns * 16 + l16) * DH_ + quad * 8;
    const bf16* Vp[4];
    #pragma unroll
    for (int ds = 0; ds < 4; ++ds) Vp[ds] = Vb + (size_t)(ds * 16 + l16) * S_ + quad * 4;

    for (int half = 0; half < 2; ++half) {
        int tile = half ? (63 - pr) : pr;
        int q0 = tile * 32;

        bf16x8 qf[2][2];
        #pragma unroll
        for (int s = 0; s < 2; ++s) {
            const bf16* qp = Qb + (size_t)(q0 + s * 16 + l16) * DH_ + quad * 8;
            qf[s][0] = *(const bf16x8*)(qp);
            qf[s][1] = *(const bf16x8*)(qp + 32);
        }

        f32x4 oacc[2][4] = {};
        f32x4 lacc[2] = {};

        int nkt = tile / 2 + 1;
        for (int kt = wave; kt < nkt; kt += 4) {
            int kv0 = kt * 64;
            bool diag = (kt == nkt - 1);

            // ---- issue ALL loads for this iteration up-front ----
            bf16x8 kf[4][2];
            #pragma unroll
            for (int ns = 0; ns < 4; ++ns) {
                const bf16* kp = Kp[ns] + (size_t)kv0 * DH_;
                kf[ns][0] = *(const bf16x8*)(kp);
                kf[ns][1] = *(const bf16x8*)(kp + 32);
            }
            bf16x4 vf[4][4];
            #pragma unroll
            for (int ns = 0; ns < 4; ++ns)
              #pragma unroll
              for (int ds = 0; ds < 4; ++ds)
                vf[ns][ds] = *(const bf16x4*)(Vp[ds] + kv0 + ns * 16);

            // ---- swapped QK^T: sacc[s][ns][r] = S[q=l16][kv=kv0+ns*16+quad*4+r] ----
            f32x4 sa0[4] = {}, sa1[4] = {};
            #pragma unroll
            for (int ns = 0; ns < 4; ++ns) {
                sa0[ns] = __builtin_amdgcn_mfma_f32_16x16x32_bf16(kf[ns][0], qf[0][0], sa0[ns], 0, 0, 0);
                sa0[ns] = __builtin_amdgcn_mfma_f32_16x16x32_bf16(kf[ns][1], qf[0][1], sa0[ns], 0, 0, 0);
            }
            #pragma unroll
            for (int ns = 0; ns < 4; ++ns) {
                sa1[ns] = __builtin_amdgcn_mfma_f32_16x16x32_bf16(kf[ns][0], qf[1][0], sa1[ns], 0, 0, 0);
                sa1[ns] = __builtin_amdgcn_mfma_f32_16x16x32_bf16(kf[ns][1], qf[1][1], sa1[ns], 0, 0, 0);
            }

            // ---- exp2 + pack to bf16x4 (stays in registers: this IS the PV A-fragment) ----
            bf16x4 pk0[4], pk1[4];
            #pragma unroll
            for (int ns = 0; ns < 4; ++ns) {
                #pragma unroll
                for (int r = 0; r < 4; ++r) {
                    float p0 = __builtin_amdgcn_exp2f(sa0[ns][r]);
                    float p1 = __builtin_amdgcn_exp2f(sa1[ns][r]);
                    if (diag) {
                        int kv = kv0 + ns * 16 + quad * 4 + r;
                        if (kv > q0 + l16)      p0 = 0.f;
                        if (kv > q0 + 16 + l16) p1 = 0.f;
                    }
                    pk0[ns][r] = (bf16)p0;
                    pk1[ns][r] = (bf16)p1;
                }
            }

            // ---- PV + row-sums, K=16 MFMAs, zero redistribution ----
            #pragma unroll
            for (int ns = 0; ns < 4; ++ns) {
                s16x4 a0 = bc4(pk0[ns]), a1 = bc4(pk1[ns]);
                lacc[0] = __builtin_amdgcn_mfma_f32_16x16x16bf16_1k(a0, onesB, lacc[0], 0, 0, 0);
                lacc[1] = __builtin_amdgcn_mfma_f32_16x16x16bf16_1k(a1, onesB, lacc[1], 0, 0, 0);
                #pragma unroll
                for (int ds = 0; ds < 4; ++ds) {
                    s16x4 vb4 = bc4(vf[ns][ds]);
                    oacc[0][ds] = __builtin_amdgcn_mfma_f32_16x16x16bf16_1k(a0, vb4, oacc[0][ds], 0, 0, 0);
                    oacc[1][ds] = __builtin_amdgcn_mfma_f32_16x16x16bf16_1k(a1, vb4, oacc[1][ds], 0, 0, 0);
                }
            }
        }

        // cross-wave reduction (pure sums) — unchanged layout/semantics
        if (l16 == 0) {
            #pragma unroll
            for (int s = 0; s < 2; ++s)
              #pragma unroll
              for (int r = 0; r < 4; ++r)
                redL[wave][s][quad][r] = lacc[s][r];
        }
        #pragma unroll
        for (int s = 0; s < 2; ++s) {
            __syncthreads();   // all waves done with prior redO reads
            #pragma unroll
            for (int ds = 0; ds < 4; ++ds)
                *(f32x4*)&redO[wave][ds][lane][0] = oacc[s][ds];
            __syncthreads();
            f32x4 osum = {};
            #pragma unroll
            for (int w = 0; w < 4; ++w)
                osum += *(const f32x4*)&redO[w][wave][lane][0];
            #pragma unroll
            for (int r = 0; r < 4; ++r) {
                float lsum = redL[0][s][quad][r] + redL[1][s][quad][r]
                           + redL[2][s][quad][r] + redL[3][s][quad][r];
                int qq = q0 + s * 16 + quad * 4 + r;
                O[((size_t)b * S_ + qq) * NDH + h * DH_ + wave * 16 + l16] = (bf16)(osum[r] / lsum);
            }
        }
        __syncthreads();   // protect redL/redO reuse by next half
    }
}

extern "C" void kernel_launch(void* const* d_in, const int* in_sizes, int n_in,
                              void* d_out, int out_size, void* d_ws, size_t ws_size,
                              hipStream_t stream) {
    const float* x  = (const float*)d_in[0];
    const float* Wq = (const float*)d_in[1];
    const float* bq = (const float*)d_in[2];
    const float* Wk = (const float*)d_in[3];
    const float* bk = (const float*)d_in[4];
    const float* Wv = (const float*)d_in[5];
    const float* bv = (const float*)d_in[6];
    const float* Wo = (const float*)d_in[7];
    const float* bo = (const float*)d_in[8];
    float* out = (float*)d_out;

    bf16* ws = (bf16*)d_ws;
    const size_t M1 = (size_t)1024 * 1024;
    bf16* xb    = ws;                   // 4M
    bf16* WqkvT = ws + 4 * M1;          // 3M contiguous (WqT|WkT|WvT)
    bf16* WoT   = ws + 7 * M1;          // 1M
    bf16* Qw    = ws + 8 * M1;          // Q|K contiguous, 4M each
    bf16* Vtw   = ws + 16 * M1;         // 4M ([bh][d][s])
    bf16* Ow    = ws + 20 * M1;         // 4M

    prep<<<8192, 256, 0, stream>>>(x, Wq, Wk, Wv, Wo,
                                   xb, WqkvT, WqkvT + M1, WqkvT + 2 * M1, WoT);

    qkv_gemm<<<dim3(3072 / 128, BS_ / 128), 256, 0, stream>>>(xb, WqkvT, bq, bk, bv, Qw, Vtw);

    flash7<<<dim3(B_ * H_, 32), 256, 0, stream>>>(Qw, Qw + PER, Vtw, Ow);

    gemm_proj<<<dim3(1024 / 64, BS_ / 128), 256, 0, stream>>>(Ow, WoT, bo, out);
}

// Round 4
// 220.012 us; speedup vs baseline: 1.1009x; 1.1009x over previous
//
#include <hip/hip_runtime.h>

#define B_  2
#define S_  2048
#define D_  1024
#define H_  16
#define DH_ 64
#define NDH (H_*DH_)   // 1024
#define BS_ (B_*S_)    // 4096
#define PER ((size_t)B_*H_*S_*DH_)   // 4M elements

typedef __bf16 bf16;
typedef bf16 bf16x8 __attribute__((ext_vector_type(8)));
typedef bf16 bf16x4 __attribute__((ext_vector_type(4)));
typedef float f32x4 __attribute__((ext_vector_type(4)));

// softmax scale folded into Q: 0.125 * log2(e); flash kernel then uses exp2
#define QSCALE 0.18033688011112042f

#define AS1 __attribute__((address_space(1)))
#define AS3 __attribute__((address_space(3)))
__device__ inline void gld16(const bf16* g, bf16* l) {
    __builtin_amdgcn_global_load_lds((const AS1 void*)g, (AS3 void*)l, 16, 0, 0);
}

// ---------------- fused prep: cast x -> bf16  +  transpose-cast 4 weight mats ----------------
__global__ __launch_bounds__(256) void prep(
        const float* __restrict__ x,
        const float* __restrict__ W0, const float* __restrict__ W1,
        const float* __restrict__ W2, const float* __restrict__ W3,
        bf16* __restrict__ xb, bf16* __restrict__ T0, bf16* __restrict__ T1,
        bf16* __restrict__ T2, bf16* __restrict__ T3) {
    __shared__ float T[32][33];
    int bid = blockIdx.x, t = threadIdx.x;
    if (bid < 4096) {
        int i = (bid * 256 + t) * 4;
        float4 v = *(const float4*)(x + i);
        bf16x4 o = { (bf16)v.x, (bf16)v.y, (bf16)v.z, (bf16)v.w };
        *(bf16x4*)(xb + i) = o;
        return;
    }
    int r2 = bid - 4096;
    int z = r2 >> 10, w = r2 & 1023;
    const float* W = (z == 0) ? W0 : (z == 1) ? W1 : (z == 2) ? W2 : W3;
    bf16* Wt = (z == 0) ? T0 : (z == 1) ? T1 : (z == 2) ? T2 : T3;
    int k0 = (w >> 5) * 32, n0 = (w & 31) * 32;
    int r = t >> 3, c = (t & 7) * 4;
    float4 v = *(const float4*)(W + (size_t)(k0 + r) * 1024 + n0 + c);
    T[c + 0][r] = v.x; T[c + 1][r] = v.y; T[c + 2][r] = v.z; T[c + 3][r] = v.w;
    __syncthreads();
    bf16x4 o = { (bf16)T[r][c], (bf16)T[r][c + 1], (bf16)T[r][c + 2], (bf16)T[r][c + 3] };
    *(bf16x4*)(Wt + (size_t)(n0 + r) * 1024 + k0 + c) = o;
}

// ---------------- fused QKV GEMM: 128x128 tile, 2-phase double-buffered (T3 min recipe) ----------------
// stage(t+1) issued BEFORE ds_read+MFMA of t; one vmcnt(0)+s_barrier per K-step.
// XCD-aware bijective swizzle (nwg=768, %8==0). Q gets QSCALE folded in (fp32, pre-round).
__global__ __launch_bounds__(256) void qkv_gemm(
        const bf16* __restrict__ A, const bf16* __restrict__ Bt,
        const float* __restrict__ bq, const float* __restrict__ bk,
        const float* __restrict__ bv, bf16* __restrict__ Qout, bf16* __restrict__ Vt) {
    __shared__ __align__(16) bf16 As[2][128 * 32];
    __shared__ __align__(16) bf16 Bs[2][128 * 32];
    int tid = threadIdx.x, wave = tid >> 6, lane = tid & 63;
    int quad = lane >> 4, l16 = lane & 15;

    int flat = blockIdx.y * 24 + blockIdx.x;          // nwg = 768
    int swz  = (flat & 7) * 96 + (flat >> 3);         // bijective: 768/8 = 96
    int bm = (swz / 24) * 128, bn = (swz % 24) * 128;
    int wm = (wave >> 1) * 64, wn = (wave & 1) * 64;

    int sr = lane >> 2, sc = (lane & 3) * 8;
    const bf16* Ag0 = A + (size_t)(bm + (wave * 2 + 0) * 16 + sr) * 1024 + sc;
    const bf16* Ag1 = A + (size_t)(bm + (wave * 2 + 1) * 16 + sr) * 1024 + sc;
    const bf16* Bg0 = Bt + (size_t)(bn + (wave * 2 + 0) * 16 + sr) * 1024 + sc;
    const bf16* Bg1 = Bt + (size_t)(bn + (wave * 2 + 1) * 16 + sr) * 1024 + sc;
    int la0 = (wave * 2 + 0) * 512;
    int la1 = (wave * 2 + 1) * 512;

    f32x4 acc[4][4] = {};

    // prologue: stage K-step 0 into buffer 0
    gld16(Ag0, &As[0][la0]);
    gld16(Ag1, &As[0][la1]);
    gld16(Bg0, &Bs[0][la0]);
    gld16(Bg1, &Bs[0][la1]);
    asm volatile("s_waitcnt vmcnt(0)" ::: "memory");
    __builtin_amdgcn_s_barrier();

    for (int t = 0; t < 32; ++t) {
        int cur = t & 1, nxt = cur ^ 1;
        if (t < 31) {
            int k0 = (t + 1) * 32;
            gld16(Ag0 + k0, &As[nxt][la0]);
            gld16(Ag1 + k0, &As[nxt][la1]);
            gld16(Bg0 + k0, &Bs[nxt][la0]);
            gld16(Bg1 + k0, &Bs[nxt][la1]);
        }
        bf16x8 af[4], bfr[4];
        #pragma unroll
        for (int i = 0; i < 4; ++i)
            af[i] = *(const bf16x8*)&As[cur][(wm + i * 16 + l16) * 32 + quad * 8];
        #pragma unroll
        for (int j = 0; j < 4; ++j)
            bfr[j] = *(const bf16x8*)&Bs[cur][(wn + j * 16 + l16) * 32 + quad * 8];
        #pragma unroll
        for (int i = 0; i < 4; ++i)
          #pragma unroll
          for (int j = 0; j < 4; ++j)
            acc[i][j] = __builtin_amdgcn_mfma_f32_16x16x32_bf16(af[i], bfr[j], acc[i][j], 0, 0, 0);
        asm volatile("s_waitcnt vmcnt(0)" ::: "memory");
        __builtin_amdgcn_s_barrier();
    }

    #pragma unroll
    for (int i = 0; i < 4; ++i)
      #pragma unroll
      for (int j = 0; j < 4; ++j) {
        int col = bn + wn + j * 16 + l16;
        float bias = (col < 1024) ? bq[col] : (col < 2048) ? bk[col - 1024] : bv[col - 2048];
        int qkv = col >> 10, cw = col & 1023;
        int hh = cw >> 6, d = cw & 63;
        int row0 = bm + wm + i * 16 + quad * 4;
        int bb = row0 >> 11, s0 = row0 & 2047;
        if (qkv < 2) {
            float scl = (qkv == 0) ? QSCALE : 1.0f;
            #pragma unroll
            for (int r = 0; r < 4; ++r)
                Qout[(size_t)qkv * PER + (((size_t)bb * H_ + hh) * S_ + s0 + r) * DH_ + d] =
                    (bf16)((acc[i][j][r] + bias) * scl);
        } else {
            bf16x4 pack;
            #pragma unroll
            for (int r = 0; r < 4; ++r) pack[r] = (bf16)(acc[i][j][r] + bias);
            *(bf16x4*)&Vt[(((size_t)bb * H_ + hh) * DH_ + d) * S_ + s0] = pack;
        }
      }
}

// ---------------- output-projection GEMM: 128x64 tile, 2-phase double-buffered, fp32 out + bias ----------------
__global__ __launch_bounds__(256) void gemm_proj(
        const bf16* __restrict__ A, const bf16* __restrict__ Bt,
        const float* __restrict__ bias, float* __restrict__ out) {
    __shared__ __align__(16) bf16 As[2][128 * 32];
    __shared__ __align__(16) bf16 Bs[2][64 * 32];
    int tid = threadIdx.x, wave = tid >> 6, lane = tid & 63;
    int quad = lane >> 4, l16 = lane & 15;

    int flat = blockIdx.y * 16 + blockIdx.x;          // nwg = 512
    int swz  = (flat & 7) * 64 + (flat >> 3);         // bijective: 512/8 = 64
    int bm = (swz / 16) * 128, bn = (swz % 16) * 64;
    int wm = (wave >> 1) * 64, wn = (wave & 1) * 32;

    int sr = lane >> 2, sc = (lane & 3) * 8;
    const bf16* Ag0 = A + (size_t)(bm + (wave * 2 + 0) * 16 + sr) * 1024 + sc;
    const bf16* Ag1 = A + (size_t)(bm + (wave * 2 + 1) * 16 + sr) * 1024 + sc;
    const bf16* Bg0 = Bt + (size_t)(bn + wave * 16 + sr) * 1024 + sc;
    int la0 = (wave * 2 + 0) * 512;
    int la1 = (wave * 2 + 1) * 512;
    int lb0 = wave * 512;

    f32x4 acc[4][2] = {};

    gld16(Ag0, &As[0][la0]);
    gld16(Ag1, &As[0][la1]);
    gld16(Bg0, &Bs[0][lb0]);
    asm volatile("s_waitcnt vmcnt(0)" ::: "memory");
    __builtin_amdgcn_s_barrier();

    for (int t = 0; t < 32; ++t) {
        int cur = t & 1, nxt = cur ^ 1;
        if (t < 31) {
            int k0 = (t + 1) * 32;
            gld16(Ag0 + k0, &As[nxt][la0]);
            gld16(Ag1 + k0, &As[nxt][la1]);
            gld16(Bg0 + k0, &Bs[nxt][lb0]);
        }
        bf16x8 af[4], bfr[2];
        #pragma unroll
        for (int i = 0; i < 4; ++i)
            af[i] = *(const bf16x8*)&As[cur][(wm + i * 16 + l16) * 32 + quad * 8];
        #pragma unroll
        for (int j = 0; j < 2; ++j)
            bfr[j] = *(const bf16x8*)&Bs[cur][(wn + j * 16 + l16) * 32 + quad * 8];
        #pragma unroll
        for (int i = 0; i < 4; ++i)
          #pragma unroll
          for (int j = 0; j < 2; ++j)
            acc[i][j] = __builtin_amdgcn_mfma_f32_16x16x32_bf16(af[i], bfr[j], acc[i][j], 0, 0, 0);
        asm volatile("s_waitcnt vmcnt(0)" ::: "memory");
        __builtin_amdgcn_s_barrier();
    }

    #pragma unroll
    for (int i = 0; i < 4; ++i)
      #pragma unroll
      for (int j = 0; j < 2; ++j) {
        int col = bn + wn + j * 16 + l16;
        float b = bias[col];
        #pragma unroll
        for (int r = 0; r < 4; ++r) {
            int row = bm + wm + i * 16 + quad * 4 + r;
            out[(size_t)row * 1024 + col] = acc[i][j][r] + b;
        }
      }
}

// ---------------- flash attention v4 (champion, restored): tile-paired, split-kv, 4 waves/block ----------------
// grid (32 bh, 32 pairs), 256 thr. Block handles q-tiles {p, 63-p}: uniform ~33 kt iters.
// No-max softmax: partial (O,l) over disjoint kv ranges sum directly.
// Only change vs round-0: Q pre-scaled by 0.125*log2e in qkv_gemm -> exp2 here (saves 32 v_mul/iter).
__global__ __launch_bounds__(256) void flash4(
        const bf16* __restrict__ Q, const bf16* __restrict__ K,
        const bf16* __restrict__ Vt, bf16* __restrict__ O) {
    int bh = blockIdx.x;
    int b = bh >> 4, h = bh & 15;
    int pr = blockIdx.y;                 // 0..31
    int tid = threadIdx.x;
    int wave = tid >> 6, lane = tid & 63;
    int quad = lane >> 4, l16 = lane & 15;

    // P (per-wave, loop phase) aliases redO (reduction phase)
    __shared__ __align__(16) char smem[4 * 2 * 16 * 72 * 2];   // 18432 B
    bf16 (*P)[2][16][72] = reinterpret_cast<bf16 (*)[2][16][72]>(smem);
    float (*redO)[4][64][4] = reinterpret_cast<float (*)[4][64][4]>(smem); // 16384 B
    __shared__ float redL[4][2][4][4];

    const bf16* Qb = Q + (size_t)bh * S_ * DH_;
    const bf16* Kb = K + (size_t)bh * S_ * DH_;
    const bf16* Vb = Vt + (size_t)bh * DH_ * S_;

    bf16x8 ones;
    #pragma unroll
    for (int j = 0; j < 8; ++j) ones[j] = (l16 == 0) ? (bf16)1.0f : (bf16)0.0f;

    for (int half = 0; half < 2; ++half) {
        int tile = half ? (63 - pr) : pr;
        int q0 = tile * 32;

        bf16x8 qf[2][2];
        #pragma unroll
        for (int s = 0; s < 2; ++s) {
            const bf16* qp = Qb + (size_t)(q0 + s * 16 + l16) * DH_ + quad * 8;
            qf[s][0] = *(const bf16x8*)(qp);
            qf[s][1] = *(const bf16x8*)(qp + 32);
        }

        f32x4 oacc[2][4] = {};
        f32x4 lacc[2] = {};

        int nkt = tile / 2 + 1;
        for (int kt = wave; kt < nkt; kt += 4) {
            int kv0 = kt * 64;
            bf16x8 kf[4][2];
            #pragma unroll
            for (int ns = 0; ns < 4; ++ns) {
                const bf16* kp = Kb + (size_t)(kv0 + ns * 16 + l16) * DH_ + quad * 8;
                kf[ns][0] = *(const bf16x8*)(kp);
                kf[ns][1] = *(const bf16x8*)(kp + 32);
            }
            f32x4 sacc[2][4] = {};
            #pragma unroll
            for (int s = 0; s < 2; ++s)
              #pragma unroll
              for (int ns = 0; ns < 4; ++ns) {
                sacc[s][ns] = __builtin_amdgcn_mfma_f32_16x16x32_bf16(qf[s][0], kf[ns][0], sacc[s][ns], 0, 0, 0);
                sacc[s][ns] = __builtin_amdgcn_mfma_f32_16x16x32_bf16(qf[s][1], kf[ns][1], sacc[s][ns], 0, 0, 0);
              }
            bool diag = (kt == nkt - 1);
            #pragma unroll
            for (int s = 0; s < 2; ++s)
              #pragma unroll
              for (int ns = 0; ns < 4; ++ns)
                #pragma unroll
                for (int r = 0; r < 4; ++r) {
                    float p = __builtin_amdgcn_exp2f(sacc[s][ns][r]);
                    if (diag) {
                        int kv = kv0 + ns * 16 + l16;
                        int qq = q0 + s * 16 + quad * 4 + r;
                        if (kv > qq) p = 0.f;
                    }
                    P[wave][s][quad * 4 + r][ns * 16 + l16] = (bf16)p;
                }
            #pragma unroll
            for (int ks = 0; ks < 2; ++ks) {
                bf16x8 pf0 = *(const bf16x8*)&P[wave][0][l16][ks * 32 + quad * 8];
                bf16x8 pf1 = *(const bf16x8*)&P[wave][1][l16][ks * 32 + quad * 8];
                lacc[0] = __builtin_amdgcn_mfma_f32_16x16x32_bf16(pf0, ones, lacc[0], 0, 0, 0);
                lacc[1] = __builtin_amdgcn_mfma_f32_16x16x32_bf16(pf1, ones, lacc[1], 0, 0, 0);
                #pragma unroll
                for (int ds = 0; ds < 4; ++ds) {
                    bf16x8 vf = *(const bf16x8*)(Vb + (size_t)(ds * 16 + l16) * S_ + kv0 + ks * 32 + quad * 8);
                    oacc[0][ds] = __builtin_amdgcn_mfma_f32_16x16x32_bf16(pf0, vf, oacc[0][ds], 0, 0, 0);
                    oacc[1][ds] = __builtin_amdgcn_mfma_f32_16x16x32_bf16(pf1, vf, oacc[1][ds], 0, 0, 0);
                }
            }
        }

        // cross-wave reduction (pure sums)
        if (l16 == 0) {
            #pragma unroll
            for (int s = 0; s < 2; ++s)
              #pragma unroll
              for (int r = 0; r < 4; ++r)
                redL[wave][s][quad][r] = lacc[s][r];
        }
        #pragma unroll
        for (int s = 0; s < 2; ++s) {
            __syncthreads();   // all waves done with P / prior redO reads
            #pragma unroll
            for (int ds = 0; ds < 4; ++ds)
                *(f32x4*)&redO[wave][ds][lane][0] = oacc[s][ds];
            __syncthreads();
            f32x4 osum = {};
            #pragma unroll
            for (int w = 0; w < 4; ++w)
                osum += *(const f32x4*)&redO[w][wave][lane][0];
            #pragma unroll
            for (int r = 0; r < 4; ++r) {
                float lsum = redL[0][s][quad][r] + redL[1][s][quad][r]
                           + redL[2][s][quad][r] + redL[3][s][quad][r];
                int qq = q0 + s * 16 + quad * 4 + r;
                O[((size_t)b * S_ + qq) * NDH + h * DH_ + wave * 16 + l16] = (bf16)(osum[r] / lsum);
            }
        }
        __syncthreads();   // protect P/redL reuse by next half
    }
}

extern "C" void kernel_launch(void* const* d_in, const int* in_sizes, int n_in,
                              void* d_out, int out_size, void* d_ws, size_t ws_size,
                              hipStream_t stream) {
    const float* x  = (const float*)d_in[0];
    const float* Wq = (const float*)d_in[1];
    const float* bq = (const float*)d_in[2];
    const float* Wk = (const float*)d_in[3];
    const float* bk = (const float*)d_in[4];
    const float* Wv = (const float*)d_in[5];
    const float* bv = (const float*)d_in[6];
    const float* Wo = (const float*)d_in[7];
    const float* bo = (const float*)d_in[8];
    float* out = (float*)d_out;

    bf16* ws = (bf16*)d_ws;
    const size_t M1 = (size_t)1024 * 1024;
    bf16* xb    = ws;                   // 4M
    bf16* WqkvT = ws + 4 * M1;          // 3M contiguous (WqT|WkT|WvT)
    bf16* WoT   = ws + 7 * M1;          // 1M
    bf16* Qw    = ws + 8 * M1;          // Q|K contiguous, 4M each
    bf16* Vtw   = ws + 16 * M1;         // 4M ([bh][d][s])
    bf16* Ow    = ws + 20 * M1;         // 4M

    prep<<<8192, 256, 0, stream>>>(x, Wq, Wk, Wv, Wo,
                                   xb, WqkvT, WqkvT + M1, WqkvT + 2 * M1, WoT);

    qkv_gemm<<<dim3(3072 / 128, BS_ / 128), 256, 0, stream>>>(xb, WqkvT, bq, bk, bv, Qw, Vtw);

    flash4<<<dim3(B_ * H_, 32), 256, 0, stream>>>(Qw, Qw + PER, Vtw, Ow);

    gemm_proj<<<dim3(1024 / 64, BS_ / 128), 256, 0, stream>>>(Ow, WoT, bo, out);
}